// Round 12
// baseline (126.495 us; speedup 1.0000x reference)
//
#include <hip/hip_runtime.h>
#include <hip/hip_bf16.h>

// MHA: B=2, S=2048, D=1024, H=16, Dh=64, causal band window 256.
// Fused cvt; GEMMs = r8-proven 2-phase BK=32 K-loop + NEW staged epilogues:
// acc -> (dead) 16KB LDS (XOR-swizzled chunks) -> 64B coalesced stores.
// Kills the ~19MB RFO FETCH from scalar scatter stores (r11 PMC) and cuts
// 64 scalar stores/thread to 8 vector stores. V written transposed+padded
// [bh][dh][2080] (r7-validated) -> attention PV uses s16x4 vector loads.
// History: r5 XCD-swz/BK64 reverted; r7/r9/r10 deep pipelines regressed
// (abandoned); r11 bank-conflict fix neutral (2-way was free, m136).

typedef __bf16 bf16x8 __attribute__((ext_vector_type(8)));
typedef float f32x4 __attribute__((ext_vector_type(4)));
typedef short s16x4 __attribute__((ext_vector_type(4)));
typedef unsigned short u16x8 __attribute__((ext_vector_type(8)));
typedef unsigned short u16x4 __attribute__((ext_vector_type(4)));

__device__ __forceinline__ unsigned short f2bf(float f) {
  unsigned int u = __builtin_bit_cast(unsigned int, f);
  u += 0x7FFFu + ((u >> 16) & 1u);   // round-to-nearest-even
  return (unsigned short)(u >> 16);
}

__device__ __forceinline__ f32x4 mfma32(bf16x8 a, bf16x8 b, f32x4 c) {
  return __builtin_amdgcn_mfma_f32_16x16x32_bf16(a, b, c, 0, 0, 0);
}
__device__ __forceinline__ f32x4 mfma16(s16x4 a, s16x4 b, f32x4 c) {
  return __builtin_amdgcn_mfma_f32_16x16x16bf16_1k(a, b, c, 0, 0, 0);
}

// async global->LDS, 16B per lane. LDS dest must be wave-uniform base
// (HW adds lane*16); global src is per-lane.
__device__ __forceinline__ void gl16(const unsigned short* gsrc,
                                     unsigned short* lds) {
  __builtin_amdgcn_global_load_lds(
      (const __attribute__((address_space(1))) unsigned int*)gsrc,
      (__attribute__((address_space(3))) unsigned int*)lds, 16, 0, 0);
}

// ---- fused converts: z<4 -> Wt[z][n][k] = bf16(W[k][n]); z==4 -> X->bf16 ---
__global__ __launch_bounds__(256) void cvt_all(
    const float* __restrict__ x,
    const float* __restrict__ Wq, const float* __restrict__ Wk,
    const float* __restrict__ Wv, const float* __restrict__ Wo,
    unsigned short* __restrict__ xb, unsigned short* __restrict__ Wt) {
  const int z = blockIdx.z;
  const int tx = threadIdx.x, ty = threadIdx.y;    // 32 x 8
  if (z == 4) {
    const int tid = (blockIdx.y * 32 + blockIdx.x) * 256 + ty * 32 + tx;
#pragma unroll
    for (int it = 0; it < 4; ++it) {
      const int i = tid + it * 262144;
      const float4 v = ((const float4*)x)[i];
      u16x4 o = { f2bf(v.x), f2bf(v.y), f2bf(v.z), f2bf(v.w) };
      *(u16x4*)(xb + (size_t)i * 4) = o;
    }
    return;
  }
  const float* W = (z == 0) ? Wq : (z == 1) ? Wk : (z == 2) ? Wv : Wo;
  unsigned short* dst = Wt + (size_t)z * 1024 * 1024;
  __shared__ float t[32][33];
  const int n0 = blockIdx.x * 32, k0 = blockIdx.y * 32;
#pragma unroll
  for (int i = 0; i < 32; i += 8)
    t[ty + i][tx] = W[(size_t)(k0 + ty + i) * 1024 + n0 + tx];
  __syncthreads();
#pragma unroll
  for (int i = 0; i < 32; i += 8)
    dst[(size_t)(n0 + ty + i) * 1024 + k0 + tx] = f2bf(t[tx][ty + i]);
}

// ------------- bf16 MFMA GEMM: C[M,N] = A[M,1024] * Bt[N,1024]^T ------------
// 128xBN tile, BK=32, 4 waves (2x2), r8 2-phase global_load_lds staging.
// Epilogue: 2 passes of 64 rows; acc -> swizzled LDS (reusing the 16KB A/B
// buffers, dead after the K-loop) -> 64B coalesced global stores.
// MODE 0 (BN=128): QKV. bias; q scaled 1/8; q,k -> [B,H,S,Dh]; v -> Vt
//   [B,H,Dh,2080] (padded transpose). Block-uniform type (128 | 1024).
// MODE 1 (BN=64):  out-proj. + bo, fp32 64B-chunk stores.
template <int BN, int MODE>
__global__ __launch_bounds__(256) void gemm_lds(
    const unsigned short* __restrict__ A, const unsigned short* __restrict__ Bt,
    const float* __restrict__ bq, const float* __restrict__ bk,
    const float* __restrict__ bv,
    unsigned short* __restrict__ q_ws, unsigned short* __restrict__ k_ws,
    unsigned short* __restrict__ vt_ws,
    const float* __restrict__ bo, float* __restrict__ outp) {
  constexpr int ACC_N = BN / 32;
  __shared__ __align__(16) unsigned short smem[8192];   // 16KB total
  unsigned short* Alds = smem;                          // 128x32 = 4096
  unsigned short* Blds = smem + 4096;                   // BNx32
  const int tid = threadIdx.x, lane = tid & 63, w = tid >> 6;
  const int lq = lane & 15, lg = lane >> 4;
  const int bm = blockIdx.x, bn = blockIdx.y;
  const int wr = (w >> 1) * 64, wc = (w & 1) * (BN / 2);

  // staging addressing: each inst = 64 lanes x 16B = 16 rows x 64B (BK=32 row)
  const int srow = lane >> 2, scol8 = (lane & 3) * 8;
  const unsigned short* Ag =
      A + (size_t)(bm * 128 + w * 32 + srow) * 1024 + scol8;
  const unsigned short* Bg =
      (BN == 128) ? Bt + (size_t)(bn * 128 + w * 32 + srow) * 1024 + scol8
                  : Bt + (size_t)(bn * 64 + w * 16 + srow) * 1024 + scol8;
  unsigned short* Al0 = Alds + (w * 32) * 32;       // wave-uniform LDS bases
  unsigned short* Al1 = Alds + (w * 32 + 16) * 32;
  unsigned short* Bl0 = (BN == 128) ? Blds + (w * 32) * 32
                                    : Blds + (w * 16) * 32;
  unsigned short* Bl1 = Blds + (w * 32 + 16) * 32;  // used only when BN==128

  f32x4 acc[4][ACC_N] = {};
  for (int kt = 0; kt < 1024; kt += 32) {
    __syncthreads();          // all waves done reading LDS from previous iter
    gl16(Ag + kt, Al0);
    gl16(Ag + kt + 16 * 1024, Al1);
    gl16(Bg + kt, Bl0);
    if (BN == 128) gl16(Bg + kt + 16 * 1024, Bl1);
    __syncthreads();          // drains vmcnt -> staged data visible
    bf16x8 af[4], bfr[ACC_N];
#pragma unroll
    for (int m = 0; m < 4; ++m)
      af[m] = *(const bf16x8*)(Alds + (wr + m * 16 + lq) * 32 + lg * 8);
#pragma unroll
    for (int n = 0; n < ACC_N; ++n)
      bfr[n] = *(const bf16x8*)(Blds + (wc + n * 16 + lq) * 32 + lg * 8);
#pragma unroll
    for (int m = 0; m < 4; ++m)
#pragma unroll
      for (int n = 0; n < ACC_N; ++n)
        acc[m][n] = mfma32(af[m], bfr[n], acc[m][n]);
  }

  // ---------------- staged epilogue (2 passes of 64 rows) -------------------
  // acc C/D layout (m89): local row = wr + m*16 + lg*4 + j, col = wc + n*16
  // + lq. Pass p holds rows of waves with (w>>1)==p. LDS chunk swizzle:
  // 16B-chunk c of row r stored at c ^ (r&15) (bf16) / c ^ (r&15) (f32,
  // float4 chunks) -> conflict-free vector reads.
  if (MODE == 0) {
    const int ttype = bn >> 3;                     // 0=q,1=k,2=v (uniform)
    const float* bias = (ttype == 0) ? bq : (ttype == 1) ? bk : bv;
    const float scalef = (ttype == 0) ? 0.125f : 1.0f;
#pragma unroll
    for (int p = 0; p < 2; ++p) {
      __syncthreads();        // previous use of smem done
      if ((w >> 1) == p) {
#pragma unroll
        for (int m = 0; m < 4; ++m)
#pragma unroll
          for (int n = 0; n < 4; ++n)
#pragma unroll
            for (int j = 0; j < 4; ++j) {
              const int lrow = m * 16 + lg * 4 + j;        // 0..63
              const int col = wc + n * 16 + lq;            // 0..127
              const float v =
                  (acc[m][n][j] + bias[(bn & 7) * 128 + col]) * scalef;
              smem[lrow * 128 + (((col >> 3) ^ (lrow & 15)) << 3) +
                   (col & 7)] = f2bf(v);
            }
      }
      __syncthreads();
      const int grow = bm * 128 + p * 64;
      const int b = grow >> 11;
      if (ttype < 2) {
        // q/k: thread -> (row, 32-dh segment); 64B contiguous store
        const int lr = tid & 63, seg = tid >> 6;
        const int s = (grow & 2047) + lr;
        const int h = (bn & 7) * 2 + (seg >> 1), dh0 = (seg & 1) * 32;
        unsigned short* dst = ((ttype == 0) ? q_ws : k_ws) +
                              ((size_t)(b * 16 + h) * 2048 + s) * 64 + dh0;
#pragma unroll
        for (int j2 = 0; j2 < 4; ++j2) {
          const int c = seg * 4 + j2;
          *(u16x8*)(dst + j2 * 8) =
              *(const u16x8*)&smem[lr * 128 + ((c ^ (lr & 15)) << 3)];
        }
      } else {
        // v: thread -> (col=dh-row, 32-s half); gather column, 64B store
        const int pair = tid >> 1, sh = tid & 1;
        const int h = (bn & 7) * 2 + (pair >> 6), dh = pair & 63;
        const int s0 = (grow & 2047) + sh * 32;
        unsigned short* dst =
            vt_ws + ((size_t)(b * 16 + h) * 64 + dh) * 2080 + s0;
#pragma unroll
        for (int i = 0; i < 4; ++i) {
          u16x8 val;
#pragma unroll
          for (int e = 0; e < 8; ++e) {
            const int lr = sh * 32 + i * 8 + e;
            val[e] = smem[lr * 128 + (((pair >> 3) ^ (lr & 15)) << 3) +
                          (pair & 7)];
          }
          *(u16x8*)(dst + i * 8) = val;
        }
      }
    }
  } else {
    float* Cf = (float*)smem;                      // 4096 floats = 16KB
#pragma unroll
    for (int p = 0; p < 2; ++p) {
      __syncthreads();
      if ((w >> 1) == p) {
#pragma unroll
        for (int m = 0; m < 4; ++m)
#pragma unroll
          for (int n = 0; n < 2; ++n)
#pragma unroll
            for (int j = 0; j < 4; ++j) {
              const int lrow = m * 16 + lg * 4 + j;        // 0..63
              const int col = wc + n * 16 + lq;            // 0..63
              Cf[lrow * 64 + (((col >> 2) ^ (lrow & 15)) << 2) + (col & 3)] =
                  acc[m][n][j] + bo[bn * 64 + col];
            }
      }
      __syncthreads();
      const int row = tid >> 2, seg = tid & 3;     // 64 rows x 4 segs
      float* dst = outp + (size_t)(bm * 128 + p * 64 + row) * 1024 +
                   bn * 64 + seg * 16;
#pragma unroll
      for (int j2 = 0; j2 < 4; ++j2) {
        const int c = seg * 4 + j2;
        ((float4*)dst)[j2] =
            *(const float4*)&Cf[row * 64 + ((c ^ (row & 15)) << 2)];
      }
    }
  }
}

// ---------------- banded flash attention ------------------------------------
// One wave per 16-query strip; 4 waves/block. Swapped QK^T: S^T = K*Q^T so
// lane owns q = lane&15. STATIC-max softmax: p = exp(s - 4) (shift-exact;
// scores ~N(0,0.41), global max ~2.3 << 4). PV: O^T = V^T * P^T via 16x16x16;
// V^T loaded as s16x4 from padded Vt [B,H,Dh,2080] (4160B stride -> no 4KiB
// channel aliasing; r7-validated). Masked lanes get p=0 explicitly.
__global__ __launch_bounds__(256) void attn_kernel(
    const unsigned short* __restrict__ q_ws,
    const unsigned short* __restrict__ k_ws,
    const unsigned short* __restrict__ vt_ws,
    unsigned short* __restrict__ attn_out) {
  __shared__ unsigned short o_lds[4][16 * 64];
  const int tid = threadIdx.x, lane = tid & 63, w = tid >> 6;
  const int lq = lane & 15, lg = lane >> 4;
  const int bh = blockIdx.y;                       // b*16 + h
  const int q0 = blockIdx.x * 64 + w * 16;
  const unsigned short* Q = q_ws + (size_t)bh * 2048 * 64;
  const unsigned short* Kp = k_ws + (size_t)bh * 2048 * 64;
  const unsigned short* Vt = vt_ws + (size_t)bh * 64 * 2080;

  const bf16x8 qf0 = *(const bf16x8*)(Q + (size_t)(q0 + lq) * 64 + lg * 8);
  const bf16x8 qf1 = *(const bf16x8*)(Q + (size_t)(q0 + lq) * 64 + 32 + lg * 8);

  float lsum = 0.f;
  f32x4 oacc[4] = {};
  int t0 = (q0 - 255) >> 4;
  if (t0 < 0) t0 = 0;
  const int t1 = q0 >> 4;

  for (int t = t0; t <= t1; ++t) {
    const int j0 = t * 16;
    const bf16x8 kf0 = *(const bf16x8*)(Kp + (size_t)(j0 + lq) * 64 + lg * 8);
    const bf16x8 kf1 =
        *(const bf16x8*)(Kp + (size_t)(j0 + lq) * 64 + 32 + lg * 8);
    f32x4 stv = {};
    stv = mfma32(kf0, qf0, stv);
    stv = mfma32(kf1, qf1, stv);   // S^T: col=q=lq, row=key=j0+lg*4+reg

    float p[4], ps = 0.f;
#pragma unroll
    for (int r = 0; r < 4; ++r) {
      const int delta = (q0 + lq) - (j0 + lg * 4 + r);
      const bool ok = (delta >= 0) && (delta < 256);
      p[r] = ok ? __expf(stv[r] - 4.0f) : 0.f;
      ps += p[r];
    }
    ps += __shfl_xor(ps, 16);
    ps += __shfl_xor(ps, 32);
    lsum += ps;

    s16x4 pb = { (short)f2bf(p[0]), (short)f2bf(p[1]),
                 (short)f2bf(p[2]), (short)f2bf(p[3]) };
#pragma unroll
    for (int c = 0; c < 4; ++c) {
      // V^T A-frag: row = d = c*16+lq, k = key = lg*4 + j (contiguous in Vt)
      const s16x4 vf =
          *(const s16x4*)(Vt + (size_t)(c * 16 + lq) * 2080 + j0 + lg * 4);
      oacc[c] = mfma16(vf, pb, oacc[c]);
    }
  }

  const float rl = 1.f / lsum;
#pragma unroll
  for (int c = 0; c < 4; ++c)
#pragma unroll
    for (int r = 0; r < 4; ++r)
      o_lds[w][lq * 64 + c * 16 + lg * 4 + r] = f2bf(oacc[c][r] * rl);
  __syncthreads();
  const int row = lane >> 2, d0 = (lane & 3) * 16;
  const u16x8 o0 = *(const u16x8*)(&o_lds[w][row * 64 + d0]);
  const u16x8 o1 = *(const u16x8*)(&o_lds[w][row * 64 + d0 + 8]);
  const size_t g =
      ((size_t)((bh >> 4) * 2048 + q0 + row)) * 1024 + (bh & 15) * 64 + d0;
  *(u16x8*)(attn_out + g) = o0;
  *(u16x8*)(attn_out + g + 8) = o1;
}

// ---------------------------------------------------------------------------
extern "C" void kernel_launch(void* const* d_in, const int* in_sizes, int n_in,
                              void* d_out, int out_size, void* d_ws,
                              size_t ws_size, hipStream_t stream) {
  const float* query = (const float*)d_in[0];
  const float* Wq = (const float*)d_in[1];
  const float* bq = (const float*)d_in[2];
  const float* Wk = (const float*)d_in[3];
  const float* bk = (const float*)d_in[4];
  const float* Wv = (const float*)d_in[5];
  const float* bv = (const float*)d_in[6];
  const float* Wo = (const float*)d_in[7];
  const float* bo = (const float*)d_in[8];
  float* outp = (float*)d_out;

  char* ws = (char*)d_ws;
  unsigned short* xbf = (unsigned short*)(ws);               // 8 MiB; reused as attn_out
  unsigned short* wt  = (unsigned short*)(ws + (8u << 20));  // 8 MiB (4 weights^T)
  unsigned short* qws = (unsigned short*)(ws + (16u << 20)); // 8 MiB
  unsigned short* kws = (unsigned short*)(ws + (24u << 20)); // 8 MiB
  unsigned short* vtw = (unsigned short*)(ws + (32u << 20)); // ~16.3 MiB (Vt padded; fit r7-proven)

  cvt_all<<<dim3(32, 32, 5), dim3(32, 8), 0, stream>>>(query, Wq, Wk, Wv, Wo,
                                                       xbf, wt);
  // fused QKV: N = 3072, 128x128 tiles
  gemm_lds<128, 0><<<dim3(32, 24), 256, 0, stream>>>(
      xbf, wt, bq, bk, bv, qws, kws, vtw, nullptr, nullptr);
  attn_kernel<<<dim3(32, 32), 256, 0, stream>>>(qws, kws, vtw, xbf);
  // output projection: N = 1024, 128x64 tile -> 512 blocks (2/CU)
  gemm_lds<64, 1><<<dim3(32, 16), 256, 0, stream>>>(
      xbf, wt + (size_t)3 * 1024 * 1024, nullptr, nullptr, nullptr, nullptr,
      nullptr, nullptr, bo, outp);
}

// Round 13
// 93.658 us; speedup vs baseline: 1.3506x; 1.3506x over previous
//
#include <hip/hip_runtime.h>
#include <hip/hip_bf16.h>

// MHA: B=2, S=2048, D=1024, H=16, Dh=64, causal band window 256.
// CHAMPION CONFIG (r8, 93.3 us) — exact revert.
// Fused cvt (X->bf16 + 4x W transpose+cvt); QKV GEMM (2-phase global_load_lds
// staging, BK=32, 128x128, fused bias + q*0.125, scatter -> [B,H,S,Dh]);
// banded flash attention with STATIC-max softmax (p = exp(s-4), shift-exact;
// scores ~N(0,0.41), max ~2.3 << 4); out GEMM 128x64.
// Tested-and-reverted this session (all regressed vs this config):
//   r5  XCD swizzle (FETCH 28.8->68.7MB: per-XCD chunking streamed all of A)
//   r5  BK=64 unswizzled (128B rows -> bank conflicts, occupancy 14%)
//   r6  one-barrier dbuf (neutral; T3 shape without T4 counted-vmcnt)
//   r7  3-buffer counted-vmcnt + sched pins (regressed: defeats compiler)
//   r9  coarse 256^2 8-wave pipeline, 1 blk/CU (568 TF < 2-phase)
//   r10 fine 4-phase 256x128, 2 blk/CU (545 TF; dual-barrier stalls)
//   r11 BK=64 + XOR swizzle (0 conflicts but slower: 2-way was free, m136)
//   r12 LDS-staged epilogues (extra barriers + gather conflicts > scatter)

typedef __bf16 bf16x8 __attribute__((ext_vector_type(8)));
typedef float f32x4 __attribute__((ext_vector_type(4)));
typedef short s16x4 __attribute__((ext_vector_type(4)));
typedef unsigned short u16x8 __attribute__((ext_vector_type(8)));
typedef unsigned short u16x4 __attribute__((ext_vector_type(4)));

__device__ __forceinline__ unsigned short f2bf(float f) {
  unsigned int u = __builtin_bit_cast(unsigned int, f);
  u += 0x7FFFu + ((u >> 16) & 1u);   // round-to-nearest-even
  return (unsigned short)(u >> 16);
}

__device__ __forceinline__ f32x4 mfma32(bf16x8 a, bf16x8 b, f32x4 c) {
  return __builtin_amdgcn_mfma_f32_16x16x32_bf16(a, b, c, 0, 0, 0);
}
__device__ __forceinline__ f32x4 mfma16(s16x4 a, s16x4 b, f32x4 c) {
  return __builtin_amdgcn_mfma_f32_16x16x16bf16_1k(a, b, c, 0, 0, 0);
}

// async global->LDS, 16B per lane. LDS dest must be wave-uniform base
// (HW adds lane*16); global src is per-lane.
__device__ __forceinline__ void gl16(const unsigned short* gsrc,
                                     unsigned short* lds) {
  __builtin_amdgcn_global_load_lds(
      (const __attribute__((address_space(1))) unsigned int*)gsrc,
      (__attribute__((address_space(3))) unsigned int*)lds, 16, 0, 0);
}

// ---- fused converts: z<4 -> Wt[z][n][k] = bf16(W[k][n]); z==4 -> X->bf16 ---
__global__ __launch_bounds__(256) void cvt_all(
    const float* __restrict__ x,
    const float* __restrict__ Wq, const float* __restrict__ Wk,
    const float* __restrict__ Wv, const float* __restrict__ Wo,
    unsigned short* __restrict__ xb, unsigned short* __restrict__ Wt) {
  const int z = blockIdx.z;
  const int tx = threadIdx.x, ty = threadIdx.y;    // 32 x 8
  if (z == 4) {
    // X: 2x2048x1024 = 4,194,304 floats = 1,048,576 float4; 262,144 threads
    const int tid = (blockIdx.y * 32 + blockIdx.x) * 256 + ty * 32 + tx;
#pragma unroll
    for (int it = 0; it < 4; ++it) {
      const int i = tid + it * 262144;
      const float4 v = ((const float4*)x)[i];
      u16x4 o = { f2bf(v.x), f2bf(v.y), f2bf(v.z), f2bf(v.w) };
      *(u16x4*)(xb + (size_t)i * 4) = o;
    }
    return;
  }
  const float* W = (z == 0) ? Wq : (z == 1) ? Wk : (z == 2) ? Wv : Wo;
  unsigned short* dst = Wt + (size_t)z * 1024 * 1024;
  __shared__ float t[32][33];
  const int n0 = blockIdx.x * 32, k0 = blockIdx.y * 32;
#pragma unroll
  for (int i = 0; i < 32; i += 8)
    t[ty + i][tx] = W[(size_t)(k0 + ty + i) * 1024 + n0 + tx];
  __syncthreads();
#pragma unroll
  for (int i = 0; i < 32; i += 8)
    dst[(size_t)(n0 + ty + i) * 1024 + k0 + tx] = f2bf(t[tx][ty + i]);
}

// ------------- bf16 MFMA GEMM: C[M,N] = A[M,1024] * Bt[N,1024]^T ------------
// 128xBN block tile, BK=32, 4 waves (2x2), global_load_lds width-16 staging
// (proven 2-phase structure).
// MODE 0 (BN=128): QKV. bias; q scaled 1/8; q,k,v -> [B,H,S,Dh]
// MODE 1 (BN=64):  out-proj. + bo, fp32 store.
template <int BN, int MODE>
__global__ __launch_bounds__(256) void gemm_lds(
    const unsigned short* __restrict__ A, const unsigned short* __restrict__ Bt,
    const float* __restrict__ bq, const float* __restrict__ bk,
    const float* __restrict__ bv,
    unsigned short* __restrict__ q_ws, unsigned short* __restrict__ k_ws,
    unsigned short* __restrict__ v_ws,
    const float* __restrict__ bo, float* __restrict__ outp) {
  constexpr int ACC_N = BN / 32;
  __shared__ unsigned short Alds[128 * 32];
  __shared__ unsigned short Blds[BN * 32];
  const int tid = threadIdx.x, lane = tid & 63, w = tid >> 6;
  const int lq = lane & 15, lg = lane >> 4;
  const int bm = blockIdx.x, bn = blockIdx.y;
  const int wr = (w >> 1) * 64, wc = (w & 1) * (BN / 2);

  // staging addressing: each inst = 64 lanes x 16B = 16 rows x 64B (BK=32 row)
  const int srow = lane >> 2, scol8 = (lane & 3) * 8;
  const unsigned short* Ag =
      A + (size_t)(bm * 128 + w * 32 + srow) * 1024 + scol8;
  const unsigned short* Bg =
      (BN == 128) ? Bt + (size_t)(bn * 128 + w * 32 + srow) * 1024 + scol8
                  : Bt + (size_t)(bn * 64 + w * 16 + srow) * 1024 + scol8;
  unsigned short* Al0 = Alds + (w * 32) * 32;       // wave-uniform LDS bases
  unsigned short* Al1 = Alds + (w * 32 + 16) * 32;
  unsigned short* Bl0 = (BN == 128) ? Blds + (w * 32) * 32
                                    : Blds + (w * 16) * 32;
  unsigned short* Bl1 = Blds + (w * 32 + 16) * 32;  // used only when BN==128

  f32x4 acc[4][ACC_N] = {};
  for (int kt = 0; kt < 1024; kt += 32) {
    __syncthreads();          // all waves done reading LDS from previous iter
    gl16(Ag + kt, Al0);
    gl16(Ag + kt + 16 * 1024, Al1);
    gl16(Bg + kt, Bl0);
    if (BN == 128) gl16(Bg + kt + 16 * 1024, Bl1);
    __syncthreads();          // drains vmcnt -> staged data visible
    bf16x8 af[4], bfr[ACC_N];
#pragma unroll
    for (int m = 0; m < 4; ++m)
      af[m] = *(const bf16x8*)(Alds + (wr + m * 16 + lq) * 32 + lg * 8);
#pragma unroll
    for (int n = 0; n < ACC_N; ++n)
      bfr[n] = *(const bf16x8*)(Blds + (wc + n * 16 + lq) * 32 + lg * 8);
#pragma unroll
    for (int m = 0; m < 4; ++m)
#pragma unroll
      for (int n = 0; n < ACC_N; ++n)
        acc[m][n] = mfma32(af[m], bfr[n], acc[m][n]);
  }

  // epilogue: C/D layout (m89): col = lane&15, row = (lane>>4)*4 + reg
  const int r0 = bm * 128 + wr + lg * 4;
  const int c0g = bn * BN + wc + lq;
#pragma unroll
  for (int m = 0; m < 4; ++m) {
#pragma unroll
    for (int n = 0; n < ACC_N; ++n) {
      const int col = c0g + n * 16;
#pragma unroll
      for (int j = 0; j < 4; ++j) {
        const int row = r0 + m * 16 + j;
        float v = acc[m][n][j];
        if (MODE == 0) {
          const int t = col >> 10, cc = col & 1023;
          const float* bias = (t == 0) ? bq : ((t == 1) ? bk : bv);
          v += bias[cc];
          if (t == 0) v *= 0.125f;  // bake in 1/sqrt(Dh)
          unsigned short* dst = (t == 0) ? q_ws : ((t == 1) ? k_ws : v_ws);
          const int h = cc >> 6, dh = cc & 63, b = row >> 11, s = row & 2047;
          dst[((size_t)(b * 16 + h) * 2048 + s) * 64 + dh] = f2bf(v);
        } else {
          outp[(size_t)row * 1024 + col] = v + bo[col];
        }
      }
    }
  }
}

// ---------------- banded flash attention ------------------------------------
// One wave per 16-query strip; 4 waves/block. Swapped QK^T: S^T = K*Q^T so
// lane owns q = lane&15. STATIC-max softmax: p = exp(s - 4) (shift-exact;
// scores ~N(0,0.41), global max ~2.3 << 4; no overflow until ~92). No running
// max, no rescale -- only the lsum cross-lane reduce remains.
// PV: O^T = V^T * P^T via 16x16x16; V gathered scalar from [B,H,S,Dh].
// Band: queries [q0,q0+15] need keys [q0-255, q0+15] -> tiles
// floor((q0-255)/16) .. q0/16 (clamped). Masked lanes get p=0 explicitly.
__global__ __launch_bounds__(256) void attn_kernel(
    const unsigned short* __restrict__ q_ws,
    const unsigned short* __restrict__ k_ws,
    const unsigned short* __restrict__ v_ws,
    unsigned short* __restrict__ attn_out) {
  __shared__ unsigned short o_lds[4][16 * 64];
  const int tid = threadIdx.x, lane = tid & 63, w = tid >> 6;
  const int lq = lane & 15, lg = lane >> 4;
  const int bh = blockIdx.y;                       // b*16 + h
  const int q0 = blockIdx.x * 64 + w * 16;
  const unsigned short* Q = q_ws + (size_t)bh * 2048 * 64;
  const unsigned short* Kp = k_ws + (size_t)bh * 2048 * 64;
  const unsigned short* Vp = v_ws + (size_t)bh * 2048 * 64;

  // Q^T B-fragments: col=q=lq, k=d contiguous 8
  const bf16x8 qf0 = *(const bf16x8*)(Q + (size_t)(q0 + lq) * 64 + lg * 8);
  const bf16x8 qf1 = *(const bf16x8*)(Q + (size_t)(q0 + lq) * 64 + 32 + lg * 8);

  float lsum = 0.f;
  f32x4 oacc[4] = {};   // O^T: d = c*16 + lg*4 + reg, q = lq
  int t0 = (q0 - 255) >> 4;   // 17-tile band span (arith shift = floor)
  if (t0 < 0) t0 = 0;
  const int t1 = q0 >> 4;

  for (int t = t0; t <= t1; ++t) {
    const int j0 = t * 16;
    const bf16x8 kf0 = *(const bf16x8*)(Kp + (size_t)(j0 + lq) * 64 + lg * 8);
    const bf16x8 kf1 =
        *(const bf16x8*)(Kp + (size_t)(j0 + lq) * 64 + 32 + lg * 8);
    f32x4 stv = {};
    stv = mfma32(kf0, qf0, stv);
    stv = mfma32(kf1, qf1, stv);   // S^T: col=q=lq, row=key=j0+lg*4+reg

    float p[4], ps = 0.f;
#pragma unroll
    for (int r = 0; r < 4; ++r) {
      const int delta = (q0 + lq) - (j0 + lg * 4 + r);
      const bool ok = (delta >= 0) && (delta < 256);
      p[r] = ok ? __expf(stv[r] - 4.0f) : 0.f;   // static shift, masked -> 0
      ps += p[r];
    }
    ps += __shfl_xor(ps, 16);
    ps += __shfl_xor(ps, 32);
    lsum += ps;

    s16x4 pb = { (short)f2bf(p[0]), (short)f2bf(p[1]),
                 (short)f2bf(p[2]), (short)f2bf(p[3]) };
#pragma unroll
    for (int c = 0; c < 4; ++c) {
      s16x4 vf;
#pragma unroll
      for (int j = 0; j < 4; ++j)
        vf[j] = (short)Vp[(size_t)(j0 + lg * 4 + j) * 64 + c * 16 + lq];
      oacc[c] = mfma16(vf, pb, oacc[c]);   // O^T: col=q=lq, row(d)=lg*4+reg
    }
  }

  const float rl = 1.f / lsum;
#pragma unroll
  for (int c = 0; c < 4; ++c)
#pragma unroll
    for (int r = 0; r < 4; ++r)
      o_lds[w][lq * 64 + c * 16 + lg * 4 + r] = f2bf(oacc[c][r] * rl);
  __syncthreads();
  // coalesced write: lane -> (row = lane>>2, 16 d's at (lane&3)*16)
  const int row = lane >> 2, d0 = (lane & 3) * 16;
  const u16x8 o0 = *(const u16x8*)(&o_lds[w][row * 64 + d0]);
  const u16x8 o1 = *(const u16x8*)(&o_lds[w][row * 64 + d0 + 8]);
  const size_t g =
      ((size_t)((bh >> 4) * 2048 + q0 + row)) * 1024 + (bh & 15) * 64 + d0;
  *(u16x8*)(attn_out + g) = o0;
  *(u16x8*)(attn_out + g + 8) = o1;
}

// ---------------------------------------------------------------------------
extern "C" void kernel_launch(void* const* d_in, const int* in_sizes, int n_in,
                              void* d_out, int out_size, void* d_ws,
                              size_t ws_size, hipStream_t stream) {
  const float* query = (const float*)d_in[0];
  const float* Wq = (const float*)d_in[1];
  const float* bq = (const float*)d_in[2];
  const float* Wk = (const float*)d_in[3];
  const float* bk = (const float*)d_in[4];
  const float* Wv = (const float*)d_in[5];
  const float* bv = (const float*)d_in[6];
  const float* Wo = (const float*)d_in[7];
  const float* bo = (const float*)d_in[8];
  float* outp = (float*)d_out;

  char* ws = (char*)d_ws;
  unsigned short* xbf = (unsigned short*)(ws);               // 8 MiB; reused as attn_out
  unsigned short* wt  = (unsigned short*)(ws + (8u << 20));  // 8 MiB (4 weights^T)
  unsigned short* qws = (unsigned short*)(ws + (16u << 20)); // 8 MiB
  unsigned short* kws = (unsigned short*)(ws + (24u << 20)); // 8 MiB
  unsigned short* vws = (unsigned short*)(ws + (32u << 20)); // 8 MiB

  cvt_all<<<dim3(32, 32, 5), dim3(32, 8), 0, stream>>>(query, Wq, Wk, Wv, Wo,
                                                       xbf, wt);
  // fused QKV: N = 3072
  gemm_lds<128, 0><<<dim3(32, 24), 256, 0, stream>>>(
      xbf, wt, bq, bk, bv, qws, kws, vws, nullptr, nullptr);
  attn_kernel<<<dim3(32, 32), 256, 0, stream>>>(qws, kws, vws, xbf);
  // output projection: N = 1024, 128x64 tile -> 512 blocks (2/CU)
  gemm_lds<64, 1><<<dim3(32, 16), 256, 0, stream>>>(
      xbf, wt + (size_t)3 * 1024 * 1024, nullptr, nullptr, nullptr, nullptr,
      nullptr, nullptr, bo, outp);
}

// Round 14
// 90.862 us; speedup vs baseline: 1.3922x; 1.0308x over previous
//
#include <hip/hip_runtime.h>
#include <hip/hip_bf16.h>

// MHA: B=2, S=2048, D=1024, H=16, Dh=64, causal band window 256.
// r8 champion (93.3 us) + ONE isolated change: out-proj GEMM moved to
// BK=64 + XOR LDS swizzle (r11-verified code path). Rationale: out-proj has
// 2x worse barrier-overhead per MFMA (8/iter vs QKV's 16) -> halving iter
// count (32->16) targets it specifically; swizzle kills the BK=64 128B-row
// conflict failure mode (r5). QKV/attn/cvt byte-identical to champion.
// Session ledger: r5 XCD-swz/BK64-linear, r6 dbuf, r7 counted-vmcnt, r9/r10
// deep pipelines, r11 both-kernel BK64 (confounded), r12 staged epilogues --
// all regressed vs r8.

typedef __bf16 bf16x8 __attribute__((ext_vector_type(8)));
typedef float f32x4 __attribute__((ext_vector_type(4)));
typedef short s16x4 __attribute__((ext_vector_type(4)));
typedef unsigned short u16x8 __attribute__((ext_vector_type(8)));
typedef unsigned short u16x4 __attribute__((ext_vector_type(4)));

__device__ __forceinline__ unsigned short f2bf(float f) {
  unsigned int u = __builtin_bit_cast(unsigned int, f);
  u += 0x7FFFu + ((u >> 16) & 1u);   // round-to-nearest-even
  return (unsigned short)(u >> 16);
}

__device__ __forceinline__ f32x4 mfma32(bf16x8 a, bf16x8 b, f32x4 c) {
  return __builtin_amdgcn_mfma_f32_16x16x32_bf16(a, b, c, 0, 0, 0);
}
__device__ __forceinline__ f32x4 mfma16(s16x4 a, s16x4 b, f32x4 c) {
  return __builtin_amdgcn_mfma_f32_16x16x16bf16_1k(a, b, c, 0, 0, 0);
}

// async global->LDS, 16B per lane. LDS dest must be wave-uniform base
// (HW adds lane*16); global src is per-lane.
__device__ __forceinline__ void gl16(const unsigned short* gsrc,
                                     unsigned short* lds) {
  __builtin_amdgcn_global_load_lds(
      (const __attribute__((address_space(1))) unsigned int*)gsrc,
      (__attribute__((address_space(3))) unsigned int*)lds, 16, 0, 0);
}

// ---- fused converts: z<4 -> Wt[z][n][k] = bf16(W[k][n]); z==4 -> X->bf16 ---
__global__ __launch_bounds__(256) void cvt_all(
    const float* __restrict__ x,
    const float* __restrict__ Wq, const float* __restrict__ Wk,
    const float* __restrict__ Wv, const float* __restrict__ Wo,
    unsigned short* __restrict__ xb, unsigned short* __restrict__ Wt) {
  const int z = blockIdx.z;
  const int tx = threadIdx.x, ty = threadIdx.y;    // 32 x 8
  if (z == 4) {
    const int tid = (blockIdx.y * 32 + blockIdx.x) * 256 + ty * 32 + tx;
#pragma unroll
    for (int it = 0; it < 4; ++it) {
      const int i = tid + it * 262144;
      const float4 v = ((const float4*)x)[i];
      u16x4 o = { f2bf(v.x), f2bf(v.y), f2bf(v.z), f2bf(v.w) };
      *(u16x4*)(xb + (size_t)i * 4) = o;
    }
    return;
  }
  const float* W = (z == 0) ? Wq : (z == 1) ? Wk : (z == 2) ? Wv : Wo;
  unsigned short* dst = Wt + (size_t)z * 1024 * 1024;
  __shared__ float t[32][33];
  const int n0 = blockIdx.x * 32, k0 = blockIdx.y * 32;
#pragma unroll
  for (int i = 0; i < 32; i += 8)
    t[ty + i][tx] = W[(size_t)(k0 + ty + i) * 1024 + n0 + tx];
  __syncthreads();
#pragma unroll
  for (int i = 0; i < 32; i += 8)
    dst[(size_t)(n0 + ty + i) * 1024 + k0 + tx] = f2bf(t[tx][ty + i]);
}

// ------------- QKV GEMM (champion r8, byte-identical) -----------------------
// 128x128 tile, BK=32, 4 waves (2x2), 2-phase global_load_lds staging.
// bias; q scaled 1/8; q,k,v -> [B,H,S,Dh].
__global__ __launch_bounds__(256) void gemm_qkv(
    const unsigned short* __restrict__ A, const unsigned short* __restrict__ Bt,
    const float* __restrict__ bq, const float* __restrict__ bk,
    const float* __restrict__ bv,
    unsigned short* __restrict__ q_ws, unsigned short* __restrict__ k_ws,
    unsigned short* __restrict__ v_ws) {
  __shared__ unsigned short Alds[128 * 32];
  __shared__ unsigned short Blds[128 * 32];
  const int tid = threadIdx.x, lane = tid & 63, w = tid >> 6;
  const int lq = lane & 15, lg = lane >> 4;
  const int bm = blockIdx.x, bn = blockIdx.y;
  const int wr = (w >> 1) * 64, wc = (w & 1) * 64;

  const int srow = lane >> 2, scol8 = (lane & 3) * 8;
  const unsigned short* Ag =
      A + (size_t)(bm * 128 + w * 32 + srow) * 1024 + scol8;
  const unsigned short* Bg =
      Bt + (size_t)(bn * 128 + w * 32 + srow) * 1024 + scol8;
  unsigned short* Al0 = Alds + (w * 32) * 32;
  unsigned short* Al1 = Alds + (w * 32 + 16) * 32;
  unsigned short* Bl0 = Blds + (w * 32) * 32;
  unsigned short* Bl1 = Blds + (w * 32 + 16) * 32;

  f32x4 acc[4][4] = {};
  for (int kt = 0; kt < 1024; kt += 32) {
    __syncthreads();
    gl16(Ag + kt, Al0);
    gl16(Ag + kt + 16 * 1024, Al1);
    gl16(Bg + kt, Bl0);
    gl16(Bg + kt + 16 * 1024, Bl1);
    __syncthreads();
    bf16x8 af[4], bfr[4];
#pragma unroll
    for (int m = 0; m < 4; ++m)
      af[m] = *(const bf16x8*)(Alds + (wr + m * 16 + lq) * 32 + lg * 8);
#pragma unroll
    for (int n = 0; n < 4; ++n)
      bfr[n] = *(const bf16x8*)(Blds + (wc + n * 16 + lq) * 32 + lg * 8);
#pragma unroll
    for (int m = 0; m < 4; ++m)
#pragma unroll
      for (int n = 0; n < 4; ++n)
        acc[m][n] = mfma32(af[m], bfr[n], acc[m][n]);
  }

  // epilogue: C/D layout (m89): col = lane&15, row = (lane>>4)*4 + reg
  const int r0 = bm * 128 + wr + lg * 4;
  const int c0g = bn * 128 + wc + lq;
#pragma unroll
  for (int m = 0; m < 4; ++m) {
#pragma unroll
    for (int n = 0; n < 4; ++n) {
      const int col = c0g + n * 16;
#pragma unroll
      for (int j = 0; j < 4; ++j) {
        const int row = r0 + m * 16 + j;
        float v = acc[m][n][j];
        const int t = col >> 10, cc = col & 1023;
        const float* bias = (t == 0) ? bq : ((t == 1) ? bk : bv);
        v += bias[cc];
        if (t == 0) v *= 0.125f;  // bake in 1/sqrt(Dh)
        unsigned short* dst = (t == 0) ? q_ws : ((t == 1) ? k_ws : v_ws);
        const int h = cc >> 6, dh = cc & 63, b = row >> 11, s = row & 2047;
        dst[((size_t)(b * 16 + h) * 2048 + s) * 64 + dh] = f2bf(v);
      }
    }
  }
}

// ------------- out-proj GEMM: 128x64 tile, BK=64 + XOR swizzle --------------
// (r11-verified path, isolated to out-proj only.) 16 iters (half the barrier
// drains of BK=32). LDS rows = 64 elems = 8 chunks of 16B; element (row, kc)
// at chunk-field kc ^ (row&7); gl16 dest linear -> source k pre-swizzled;
// frag read chunk-field (kk*4+lg)^(lq&7) -> 0 bank conflicts (r11 PMC).
__global__ __launch_bounds__(256) void gemm_out(
    const unsigned short* __restrict__ A, const unsigned short* __restrict__ Bt,
    const float* __restrict__ bo, float* __restrict__ outp) {
  __shared__ __align__(16) unsigned short Alds[128 * 64];
  __shared__ __align__(16) unsigned short Blds[64 * 64];
  const int tid = threadIdx.x, lane = tid & 63, w = tid >> 6;
  const int lq = lane & 15, lg = lane >> 4;
  const int bm = blockIdx.x, bn = blockIdx.y;
  const int wr = (w >> 1) * 64, wc = (w & 1) * 32;

  const int lrow = lane >> 3;                      // row within 8-row chunk
  const int ksw = (((lane & 7) ^ lrow) << 3);      // pre-swizzled source k
  const unsigned short* Ag =
      A + (size_t)(bm * 128 + w * 32 + lrow) * 1024 + ksw;
  const unsigned short* Bg =
      Bt + (size_t)(bn * 64 + w * 16 + lrow) * 1024 + ksw;
  unsigned short* AlW = Alds + (w * 32) * 64;
  unsigned short* BlW = Blds + (w * 16) * 64;
  const int cs = lq & 7;

  f32x4 acc[4][2] = {};
  for (int kt = 0; kt < 1024; kt += 64) {
    __syncthreads();
#pragma unroll
    for (int i = 0; i < 4; ++i)
      gl16(Ag + kt + (size_t)i * 8 * 1024, AlW + i * 8 * 64);
#pragma unroll
    for (int i = 0; i < 2; ++i)
      gl16(Bg + kt + (size_t)i * 8 * 1024, BlW + i * 8 * 64);
    __syncthreads();
#pragma unroll
    for (int kk = 0; kk < 2; ++kk) {
      bf16x8 af[4], bfr[2];
#pragma unroll
      for (int m = 0; m < 4; ++m)
        af[m] = *(const bf16x8*)(Alds + (wr + m * 16 + lq) * 64 +
                                 (((kk * 4 + lg) ^ cs) << 3));
#pragma unroll
      for (int n = 0; n < 2; ++n)
        bfr[n] = *(const bf16x8*)(Blds + (wc + n * 16 + lq) * 64 +
                                  (((kk * 4 + lg) ^ cs) << 3));
#pragma unroll
      for (int m = 0; m < 4; ++m)
#pragma unroll
        for (int n = 0; n < 2; ++n)
          acc[m][n] = mfma32(af[m], bfr[n], acc[m][n]);
    }
  }

  const int r0 = bm * 128 + wr + lg * 4;
  const int c0g = bn * 64 + wc + lq;
#pragma unroll
  for (int m = 0; m < 4; ++m)
#pragma unroll
    for (int n = 0; n < 2; ++n) {
      const int col = c0g + n * 16;
#pragma unroll
      for (int j = 0; j < 4; ++j)
        outp[(size_t)(r0 + m * 16 + j) * 1024 + col] = acc[m][n][j] + bo[col];
    }
}

// ---------------- banded flash attention (champion r8) ----------------------
// One wave per 16-query strip; 4 waves/block. Swapped QK^T: S^T = K*Q^T so
// lane owns q = lane&15. STATIC-max softmax: p = exp(s - 4) (shift-exact;
// scores ~N(0,0.41), global max ~2.3 << 4). PV: O^T = V^T * P^T via 16x16x16;
// V gathered scalar from [B,H,S,Dh]. Masked lanes get p=0 explicitly.
__global__ __launch_bounds__(256) void attn_kernel(
    const unsigned short* __restrict__ q_ws,
    const unsigned short* __restrict__ k_ws,
    const unsigned short* __restrict__ v_ws,
    unsigned short* __restrict__ attn_out) {
  __shared__ unsigned short o_lds[4][16 * 64];
  const int tid = threadIdx.x, lane = tid & 63, w = tid >> 6;
  const int lq = lane & 15, lg = lane >> 4;
  const int bh = blockIdx.y;                       // b*16 + h
  const int q0 = blockIdx.x * 64 + w * 16;
  const unsigned short* Q = q_ws + (size_t)bh * 2048 * 64;
  const unsigned short* Kp = k_ws + (size_t)bh * 2048 * 64;
  const unsigned short* Vp = v_ws + (size_t)bh * 2048 * 64;

  const bf16x8 qf0 = *(const bf16x8*)(Q + (size_t)(q0 + lq) * 64 + lg * 8);
  const bf16x8 qf1 = *(const bf16x8*)(Q + (size_t)(q0 + lq) * 64 + 32 + lg * 8);

  float lsum = 0.f;
  f32x4 oacc[4] = {};   // O^T: d = c*16 + lg*4 + reg, q = lq
  int t0 = (q0 - 255) >> 4;   // 17-tile band span (arith shift = floor)
  if (t0 < 0) t0 = 0;
  const int t1 = q0 >> 4;

  for (int t = t0; t <= t1; ++t) {
    const int j0 = t * 16;
    const bf16x8 kf0 = *(const bf16x8*)(Kp + (size_t)(j0 + lq) * 64 + lg * 8);
    const bf16x8 kf1 =
        *(const bf16x8*)(Kp + (size_t)(j0 + lq) * 64 + 32 + lg * 8);
    f32x4 stv = {};
    stv = mfma32(kf0, qf0, stv);
    stv = mfma32(kf1, qf1, stv);   // S^T: col=q=lq, row=key=j0+lg*4+reg

    float p[4], ps = 0.f;
#pragma unroll
    for (int r = 0; r < 4; ++r) {
      const int delta = (q0 + lq) - (j0 + lg * 4 + r);
      const bool ok = (delta >= 0) && (delta < 256);
      p[r] = ok ? __expf(stv[r] - 4.0f) : 0.f;   // static shift, masked -> 0
      ps += p[r];
    }
    ps += __shfl_xor(ps, 16);
    ps += __shfl_xor(ps, 32);
    lsum += ps;

    s16x4 pb = { (short)f2bf(p[0]), (short)f2bf(p[1]),
                 (short)f2bf(p[2]), (short)f2bf(p[3]) };
#pragma unroll
    for (int c = 0; c < 4; ++c) {
      s16x4 vf;
#pragma unroll
      for (int j = 0; j < 4; ++j)
        vf[j] = (short)Vp[(size_t)(j0 + lg * 4 + j) * 64 + c * 16 + lq];
      oacc[c] = mfma16(vf, pb, oacc[c]);   // O^T: col=q=lq, row(d)=lg*4+reg
    }
  }

  const float rl = 1.f / lsum;
#pragma unroll
  for (int c = 0; c < 4; ++c)
#pragma unroll
    for (int r = 0; r < 4; ++r)
      o_lds[w][lq * 64 + c * 16 + lg * 4 + r] = f2bf(oacc[c][r] * rl);
  __syncthreads();
  const int row = lane >> 2, d0 = (lane & 3) * 16;
  const u16x8 o0 = *(const u16x8*)(&o_lds[w][row * 64 + d0]);
  const u16x8 o1 = *(const u16x8*)(&o_lds[w][row * 64 + d0 + 8]);
  const size_t g =
      ((size_t)((bh >> 4) * 2048 + q0 + row)) * 1024 + (bh & 15) * 64 + d0;
  *(u16x8*)(attn_out + g) = o0;
  *(u16x8*)(attn_out + g + 8) = o1;
}

// ---------------------------------------------------------------------------
extern "C" void kernel_launch(void* const* d_in, const int* in_sizes, int n_in,
                              void* d_out, int out_size, void* d_ws,
                              size_t ws_size, hipStream_t stream) {
  const float* query = (const float*)d_in[0];
  const float* Wq = (const float*)d_in[1];
  const float* bq = (const float*)d_in[2];
  const float* Wk = (const float*)d_in[3];
  const float* bk = (const float*)d_in[4];
  const float* Wv = (const float*)d_in[5];
  const float* bv = (const float*)d_in[6];
  const float* Wo = (const float*)d_in[7];
  const float* bo = (const float*)d_in[8];
  float* outp = (float*)d_out;

  char* ws = (char*)d_ws;
  unsigned short* xbf = (unsigned short*)(ws);               // 8 MiB; reused as attn_out
  unsigned short* wt  = (unsigned short*)(ws + (8u << 20));  // 8 MiB (4 weights^T)
  unsigned short* qws = (unsigned short*)(ws + (16u << 20)); // 8 MiB
  unsigned short* kws = (unsigned short*)(ws + (24u << 20)); // 8 MiB
  unsigned short* vws = (unsigned short*)(ws + (32u << 20)); // 8 MiB

  cvt_all<<<dim3(32, 32, 5), dim3(32, 8), 0, stream>>>(query, Wq, Wk, Wv, Wo,
                                                       xbf, wt);
  // fused QKV: N = 3072 (champion structure)
  gemm_qkv<<<dim3(32, 24), 256, 0, stream>>>(xbf, wt, bq, bk, bv, qws, kws,
                                             vws);
  attn_kernel<<<dim3(32, 32), 256, 0, stream>>>(qws, kws, vws, xbf);
  // output projection: 128x64 tile, BK=64+swizzle, 512 blocks (2/CU)
  gemm_out<<<dim3(32, 16), 256, 0, stream>>>(
      xbf, wt + (size_t)3 * 1024 * 1024, bo, outp);
}